// Round 1
// baseline (99.131 us; speedup 1.0000x reference)
//
#include <hip/hip_runtime.h>

#define B_SZ 8192
#define L_SZ 128
#define P_PAIRS 4096
#define NR 4                      // gram rows computed; first 2 rows provably suffice
#define NC (NR * B_SZ)            // 32768 prefix entries
#define MARGIN 64.0f

// ws layout (bytes):
//   [0, 524)        float acc[131]: 0=pos_loss, 1=neg_loss, 2=quant_sum, 3..130=colsum[128]
//   [1024, 33792)   unsigned char mask[NC]   (positive-pair mask, prefix rows only)
//   [33792, 164864) float gram[NC]           (gram rows 0..NR-1)
#define WS_MASK_OFF 1024
#define WS_GRAM_OFF 33792
#define WS_ZERO_BYTES 33792

__global__ void k_mask(const int* __restrict__ pos, unsigned char* __restrict__ mask) {
    int p = blockIdx.x * blockDim.x + threadIdx.x;
    if (p >= P_PAIRS) return;
    int q = pos[2 * p], d = pos[2 * p + 1];
    if (q < NR) mask[q * B_SZ + d] = 1;
    if (d < NR) mask[d * B_SZ + q] = 1;
}

// gram[i,j] = dot(bin[i], bin[j]) for i in [0,NR). One thread per output.
// grid = NC/256 blocks; each block shares a single row i (256 <= 8192).
__global__ void k_gram(const float* __restrict__ bin, float* __restrict__ gram) {
    __shared__ float rowi[L_SZ];
    int t = blockIdx.x * 256 + threadIdx.x;
    int i = t >> 13;              // / 8192
    int j = t & (B_SZ - 1);
    if (threadIdx.x < L_SZ) rowi[threadIdx.x] = bin[i * L_SZ + threadIdx.x];
    __syncthreads();
    const float4* rj = (const float4*)(bin + (long)j * L_SZ);
    const float4* ri = (const float4*)rowi;
    float s = 0.f;
#pragma unroll
    for (int k = 0; k < L_SZ / 4; ++k) {
        float4 a = ri[k], b = rj[k];
        s += a.x * b.x + a.y * b.y + a.z * b.z + a.w * b.w;
    }
    gram[t] = s;
}

// One wave per pair (strided). 64 blocks x 256 threads = 256 waves, 16 pairs each.
__global__ void k_pos(const float* __restrict__ bin, const int* __restrict__ pos,
                      float* __restrict__ acc) {
    int lane = threadIdx.x & 63;
    int wv = threadIdx.x >> 6;
    int gw = blockIdx.x * 4 + wv;
    float contrib = 0.f;
    for (int p = gw; p < P_PAIRS; p += 256) {
        int q = pos[2 * p], d = pos[2 * p + 1];
        const float* rq = bin + (long)q * L_SZ;
        const float* rd = bin + (long)d * L_SZ;
        float s = rq[lane] * rd[lane] + rq[lane + 64] * rd[lane + 64];
#pragma unroll
        for (int o = 32; o; o >>= 1) s += __shfl_down(s, o);
        if (lane == 0) {
            float m = fmaxf(MARGIN - s, 0.f);
            contrib += m * m;
        }
    }
    __shared__ float sw[4];
    if (lane == 0) sw[wv] = contrib;
    __syncthreads();
    if (threadIdx.x == 0) atomicAdd(&acc[0], sw[0] + sw[1] + sw[2] + sw[3]);
}

// sum |abs(x)-1| over B*L floats (float4 grid-stride), block-reduce -> 1 atomic.
__global__ void k_quant(const float* __restrict__ ch, float* __restrict__ acc) {
    const int N4 = (B_SZ * L_SZ) / 4;         // 262144
    int idx = blockIdx.x * blockDim.x + threadIdx.x;
    int nthreads = gridDim.x * blockDim.x;
    const float4* c4 = (const float4*)ch;
    float s = 0.f;
    for (int k = idx; k < N4; k += nthreads) {
        float4 v = c4[k];
        s += fabsf(fabsf(v.x) - 1.f) + fabsf(fabsf(v.y) - 1.f) +
             fabsf(fabsf(v.z) - 1.f) + fabsf(fabsf(v.w) - 1.f);
    }
#pragma unroll
    for (int o = 32; o; o >>= 1) s += __shfl_down(s, o);
    __shared__ float sw[4];
    if ((threadIdx.x & 63) == 0) sw[threadIdx.x >> 6] = s;
    __syncthreads();
    if (threadIdx.x == 0) atomicAdd(&acc[2], sw[0] + sw[1] + sw[2] + sw[3]);
}

// column sums of bin (B x 128). 32 blocks x 256 rows each; coalesced.
__global__ void k_bits(const float* __restrict__ bin, float* __restrict__ acc) {
    int t = threadIdx.x;
    int col = t & 127, half = t >> 7;
    int base = blockIdx.x * 256;              // rows per block = 256
    float s = 0.f;
    for (int r = 0; r < 256; r += 2) {
        s += bin[(long)(base + r + half) * L_SZ + col];
    }
    __shared__ float sh[256];
    sh[t] = s;
    __syncthreads();
    if (t < 128) atomicAdd(&acc[3 + col], sh[t] + sh[t + 128]);
}

// Single-block exact prefix selection: first P_PAIRS candidates in flat order.
__global__ void k_scan(const unsigned char* __restrict__ mask,
                       const float* __restrict__ gram, float* __restrict__ acc) {
    const int T = 1024, PER = NC / T;          // 32 entries/thread
    int t = threadIdx.x;
    int base = t * PER;
    int cnt = 0;
    unsigned int candbits = 0;
    for (int e = 0; e < PER; ++e) {
        int k = base + e;
        int i = k >> 13, j = k & (B_SZ - 1);
        bool c = (j != i) && (mask[k] == 0);
        candbits |= (unsigned int)c << e;
        cnt += c;
    }
    // block-wide exclusive prefix of cnt
    int lane = t & 63, wv = t >> 6;
    int x = cnt;
#pragma unroll
    for (int o = 1; o < 64; o <<= 1) {
        int y = __shfl_up(x, o);
        if (lane >= o) x += y;
    }
    __shared__ int wtot[16], woff[16];
    if (lane == 63) wtot[wv] = x;
    __syncthreads();
    if (t == 0) {
        int s = 0;
        for (int w = 0; w < 16; ++w) { woff[w] = s; s += wtot[w]; }
    }
    __syncthreads();
    int rank = woff[wv] + x - cnt;            // exclusive prefix (candidates before me)
    float sum = 0.f;
    for (int e = 0; e < PER; ++e) {
        if ((candbits >> e) & 1u) {
            ++rank;                            // inclusive rank, matches csum<=P
            if (rank <= P_PAIRS) {
                float v = fmaxf(gram[base + e] + MARGIN, 0.f);
                sum += v * v;
            }
        }
    }
#pragma unroll
    for (int o = 32; o; o >>= 1) sum += __shfl_down(sum, o);
    __shared__ float wsum[16];
    if (lane == 0) wsum[wv] = sum;
    __syncthreads();
    if (t == 0) {
        float s = 0.f;
        for (int w = 0; w < 16; ++w) s += wsum[w];
        acc[1] = s;
    }
}

__global__ void k_final(const float* __restrict__ acc, float* __restrict__ out) {
    int t = threadIdx.x;                      // 128 threads
    float m = acc[3 + t] * (1.0f / (float)B_SZ);
    float v = m * m;
#pragma unroll
    for (int o = 32; o; o >>= 1) v += __shfl_down(v, o);
    __shared__ float ws2[2];
    if ((t & 63) == 0) ws2[t >> 6] = v;
    __syncthreads();
    if (t == 0) {
        float bb = ws2[0] + ws2[1];
        // num_neg = P deterministically (B^2-B >> P)
        float sim = (acc[0] + acc[1]) / (float)(P_PAIRS + P_PAIRS);
        float quant = acc[2] * (1.0f / (float)(B_SZ * L_SZ));
        out[0] = 1.0f * sim + 0.5f * quant + 0.1f * bb;
    }
}

extern "C" void kernel_launch(void* const* d_in, const int* in_sizes, int n_in,
                              void* d_out, int out_size, void* d_ws, size_t ws_size,
                              hipStream_t stream) {
    const float* bin = (const float*)d_in[0];
    const float* cont = (const float*)d_in[1];
    const int* pos = (const int*)d_in[2];
    float* out = (float*)d_out;
    float* acc = (float*)d_ws;
    unsigned char* mask = (unsigned char*)d_ws + WS_MASK_OFF;
    float* gram = (float*)((char*)d_ws + WS_GRAM_OFF);

    hipMemsetAsync(d_ws, 0, WS_ZERO_BYTES, stream);
    k_mask<<<(P_PAIRS + 255) / 256, 256, 0, stream>>>(pos, mask);
    k_gram<<<NC / 256, 256, 0, stream>>>(bin, gram);
    k_pos<<<64, 256, 0, stream>>>(bin, pos, acc);
    k_quant<<<128, 256, 0, stream>>>(cont, acc);
    k_bits<<<32, 256, 0, stream>>>(bin, acc);
    k_scan<<<1, 1024, 0, stream>>>(mask, gram, acc);
    k_final<<<1, 128, 0, stream>>>(acc, out);
}

// Round 2
// 80.939 us; speedup vs baseline: 1.2248x; 1.2248x over previous
//
#include <hip/hip_runtime.h>

#define B_SZ 8192
#define L_SZ 128
#define P_PAIRS 4096
#define NR 2                       // gram rows computed; rows 0..1 provably contain >=8190 candidates >= 4096
#define NC (NR * B_SZ)             // 16384 prefix entries
#define MARGIN 64.0f

// ws float-offsets (no zero-init needed: kernel A overwrites every slot each call)
#define POS_OFF   0                // 512 floats: per-wave pos-hinge partials
#define QUANT_OFF 512              // 128 floats: per-block quant partials
#define BITS_OFF  640              // 64*128 floats: bits_part[block][col]
#define GRAM_OFF  8832             // 16384 floats: gram rows 0..1

// ---- Kernel A: all parallel work, role by block range --------------------
//  [0,64)    gram rows 0..1        (16384 dot-128 products)
//  [64,192)  pos-pair hinge        (512 waves x 8 pairs)
//  [192,320) quant |abs(x)-1| sum  (grid-stride float4)
//  [320,384) bit colsums           (64 blocks x 128 rows)
__global__ __launch_bounds__(256) void k_all(const float* __restrict__ bin,
                                             const float* __restrict__ cont,
                                             const int* __restrict__ pos,
                                             float* __restrict__ ws) {
    const int bid = blockIdx.x, tid = threadIdx.x;
    const int lane = tid & 63, wv = tid >> 6;

    if (bid < 64) {                                   // ---- gram ----
        __shared__ float rowi[L_SZ];
        int t = bid * 256 + tid;                      // entry in [0,16384)
        int i = bid >> 5;                             // row const per block
        int j = t & (B_SZ - 1);
        if (tid < L_SZ) rowi[tid] = bin[i * L_SZ + tid];
        __syncthreads();
        const float4* rj = (const float4*)(bin + (long)j * L_SZ);
        const float4* ri = (const float4*)rowi;
        float s = 0.f;
#pragma unroll
        for (int k = 0; k < L_SZ / 4; ++k) {
            float4 a = ri[k], b = rj[k];
            s += a.x * b.x + a.y * b.y + a.z * b.z + a.w * b.w;
        }
        ws[GRAM_OFF + t] = s;
    } else if (bid < 192) {                           // ---- pos pairs ----
        int w = (bid - 64) * 4 + wv;                  // wave id [0,512)
        float contrib = 0.f;
        for (int p = w; p < P_PAIRS; p += 512) {
            int q = pos[2 * p], d = pos[2 * p + 1];
            const float* rq = bin + (long)q * L_SZ;
            const float* rd = bin + (long)d * L_SZ;
            float s = rq[lane] * rd[lane] + rq[lane + 64] * rd[lane + 64];
#pragma unroll
            for (int o = 32; o; o >>= 1) s += __shfl_down(s, o);
            if (lane == 0) {
                float m = fmaxf(MARGIN - s, 0.f);
                contrib += m * m;
            }
        }
        if (lane == 0) ws[POS_OFF + w] = contrib;
    } else if (bid < 320) {                           // ---- quant ----
        const int N4 = (B_SZ * L_SZ) / 4;             // 262144
        int idx = (bid - 192) * 256 + tid;            // stride 32768 -> 8 iters
        const float4* c4 = (const float4*)cont;
        float s = 0.f;
#pragma unroll
        for (int k = 0; k < 8; ++k) {
            float4 v = c4[idx + k * 32768];
            s += fabsf(fabsf(v.x) - 1.f) + fabsf(fabsf(v.y) - 1.f) +
                 fabsf(fabsf(v.z) - 1.f) + fabsf(fabsf(v.w) - 1.f);
        }
#pragma unroll
        for (int o = 32; o; o >>= 1) s += __shfl_down(s, o);
        __shared__ float sw[4];
        if (lane == 0) sw[wv] = s;
        __syncthreads();
        if (tid == 0) ws[QUANT_OFF + (bid - 192)] = sw[0] + sw[1] + sw[2] + sw[3];
    } else {                                          // ---- bit colsums ----
        int b = bid - 320;                            // 64 blocks, 128 rows each
        int col = tid & 127, half = tid >> 7;
        long base = (long)b * 128;
        float s = 0.f;
        for (int r = half; r < 128; r += 2)
            s += bin[(base + r) * L_SZ + col];
        __shared__ float sh[256];
        sh[tid] = s;
        __syncthreads();
        if (tid < 128) ws[BITS_OFF + b * 128 + tid] = sh[tid] + sh[tid + 128];
    }
}

// ---- Kernel B: mask-build (LDS bitmask) + exact prefix select + combine ---
__global__ __launch_bounds__(1024) void k_fin(const int* __restrict__ pos,
                                              const float* __restrict__ ws,
                                              float* __restrict__ out) {
    const int t = threadIdx.x;
    const int lane = t & 63, wv = t >> 6;
    __shared__ unsigned int lmask[NC / 32];           // 512 words = 2 KB
    __shared__ int wtot[16], woff[16];
    __shared__ float sh[1024];

    if (t < NC / 32) lmask[t] = 0u;
    __syncthreads();
#pragma unroll
    for (int r = 0; r < 4; ++r) {                     // 4096 pairs / 1024 threads
        int p = r * 1024 + t;
        int q = pos[2 * p], d = pos[2 * p + 1];
        if (q < NR) { int k = q * B_SZ + d; atomicOr(&lmask[k >> 5], 1u << (k & 31)); }
        if (d < NR) { int k = d * B_SZ + q; atomicOr(&lmask[k >> 5], 1u << (k & 31)); }
    }
    __syncthreads();

    // --- candidate bits + count over my 16 entries ---
    const int PER = NC / 1024;                        // 16
    int base = t * PER;
    const float4* g4 = (const float4*)(ws + GRAM_OFF + base);
    float4 gv[4];
#pragma unroll
    for (int k = 0; k < 4; ++k) gv[k] = g4[k];
    unsigned int candbits = 0;
    int cnt = 0;
#pragma unroll
    for (int e = 0; e < PER; ++e) {
        int k = base + e;
        int i = k >> 13, j = k & (B_SZ - 1);
        bool c = (j != i) && !((lmask[k >> 5] >> (k & 31)) & 1u);
        candbits |= (unsigned int)c << e;
        cnt += c;
    }
    // --- block-wide inclusive scan of cnt ---
    int x = cnt;
#pragma unroll
    for (int o = 1; o < 64; o <<= 1) {
        int y = __shfl_up(x, o);
        if (lane >= o) x += y;
    }
    if (lane == 63) wtot[wv] = x;
    __syncthreads();
    if (t == 0) {
        int s = 0;
        for (int w = 0; w < 16; ++w) { woff[w] = s; s += wtot[w]; }
    }
    __syncthreads();
    int rank = woff[wv] + x - cnt;                    // exclusive prefix
    float neg = 0.f;
    const float* gf = (const float*)gv;
#pragma unroll
    for (int e = 0; e < PER; ++e) {
        if ((candbits >> e) & 1u) {
            ++rank;
            if (rank <= P_PAIRS) {
                float v = fmaxf(gf[e] + MARGIN, 0.f);
                neg += v * v;
            }
        }
    }

    // --- bit-balance two-stage partial reduce: 8 groups x 128 cols ---
    {
        int col = t & 127, g = t >> 7;                // g in [0,8)
        float s = 0.f;
#pragma unroll
        for (int b = 0; b < 8; ++b)
            s += ws[BITS_OFF + (g * 8 + b) * 128 + col];
        sh[t] = s;
    }
    __syncthreads();

    // --- single combined weighted reduction ---
    const float inv2p = 1.0f / (float)(2 * P_PAIRS);
    float val = neg * inv2p;
    if (t < 512) val += ws[POS_OFF + t] * inv2p;
    if (t < 128) {
        val += ws[QUANT_OFF + t] * (0.5f / (float)(B_SZ * L_SZ));
        float cs = 0.f;
#pragma unroll
        for (int g = 0; g < 8; ++g) cs += sh[g * 128 + t];
        float m = cs * (1.0f / (float)B_SZ);
        val += 0.1f * m * m;
    }
    __syncthreads();                                  // sh reuse barrier
#pragma unroll
    for (int o = 32; o; o >>= 1) val += __shfl_down(val, o);
    if (lane == 0) sh[wv] = val;
    __syncthreads();
    if (t == 0) {
        float s = 0.f;
        for (int w = 0; w < 16; ++w) s += sh[w];
        out[0] = s;
    }
}

extern "C" void kernel_launch(void* const* d_in, const int* in_sizes, int n_in,
                              void* d_out, int out_size, void* d_ws, size_t ws_size,
                              hipStream_t stream) {
    const float* bin = (const float*)d_in[0];
    const float* cont = (const float*)d_in[1];
    const int* pos = (const int*)d_in[2];
    float* ws = (float*)d_ws;
    float* out = (float*)d_out;

    k_all<<<384, 256, 0, stream>>>(bin, cont, pos, ws);
    k_fin<<<1, 1024, 0, stream>>>(pos, ws, out);
}

// Round 3
// 79.116 us; speedup vs baseline: 1.2530x; 1.0231x over previous
//
#include <hip/hip_runtime.h>

#define B_SZ 8192
#define L_SZ 128
#define P_PAIRS 4096
#define NBLK_G 64                  // gram blocks; entries = rows 0..1 of gram
#define NC (NBLK_G * 256)          // 16384 prefix entries (>=8190 candidates guaranteed)
#define MARGIN 64.0f

// 4-byte-word offsets into ws
#define CNT_OFF   0                // int[64]     per-gram-block candidate count
#define CB_OFF    64               // u64[64*4]   per-block 256-bit candmask (512 words, byte 256, 8-aligned)
#define POS_OFF   576              // float[512]  per-wave pos-hinge partials
#define QUANT_OFF 1088             // float[128]  per-block quant partials
#define BITS_OFF  1216             // float[64*128] bit colsum partials
#define VSUM_OFF  9408             // float[64]   per-block full candidate v^2 sum
#define GRAM_OFF  9472             // float[16384] gram rows 0..1

// ---- Kernel A: all parallel work, role by block range --------------------
__global__ __launch_bounds__(256) void k_all(const float* __restrict__ bin,
                                             const float* __restrict__ cont,
                                             const int* __restrict__ pos,
                                             void* __restrict__ wsv) {
    float* ws_f = (float*)wsv;
    int* ws_i = (int*)wsv;
    const int bid = blockIdx.x, tid = threadIdx.x;
    const int lane = tid & 63, wv = tid >> 6;

    if (bid < NBLK_G) {                               // ---- gram + cand/count/vsum ----
        __shared__ float rowi[L_SZ];
        __shared__ unsigned char flag[256];
        __shared__ float rsum[4];
        __shared__ int rcnt[4];
        const int b = bid;
        const int i = b >> 5;                          // row 0 or 1
        const int jbase = (b & 31) * 256;
        flag[tid] = 0;
        if (tid < L_SZ) rowi[tid] = bin[i * L_SZ + tid];
        __syncthreads();
        const int2* pp = (const int2*)pos;
#pragma unroll
        for (int r = 0; r < P_PAIRS / 256; ++r) {      // mark positives hitting my range
            int2 qd = pp[r * 256 + tid];
            if (qd.x == i) { int dj = qd.y - jbase; if ((unsigned)dj < 256u) flag[dj] = 1; }
            if (qd.y == i) { int dj = qd.x - jbase; if ((unsigned)dj < 256u) flag[dj] = 1; }
        }
        __syncthreads();
        const int j = jbase + tid;
        const float4* rj = (const float4*)(bin + (long)j * L_SZ);
        const float4* ri4 = (const float4*)rowi;
        float s = 0.f;
#pragma unroll
        for (int k = 0; k < 32; ++k) {
            float4 a = ri4[k], c = rj[k];
            s += a.x * c.x + a.y * c.y + a.z * c.z + a.w * c.w;
        }
        ws_f[GRAM_OFF + b * 256 + tid] = s;
        const bool cand = (j != i) && !flag[tid];
        unsigned long long bm = __ballot(cand);
        if (lane == 0)
            ((unsigned long long*)(ws_i + CB_OFF))[b * 4 + wv] = bm;
        float v = cand ? fmaxf(s + MARGIN, 0.f) : 0.f;
        v = v * v;
        int cnt = cand ? 1 : 0;
#pragma unroll
        for (int o = 32; o; o >>= 1) { v += __shfl_down(v, o); cnt += __shfl_down(cnt, o); }
        if (lane == 0) { rsum[wv] = v; rcnt[wv] = cnt; }
        __syncthreads();
        if (tid == 0) {
            ws_f[VSUM_OFF + b] = rsum[0] + rsum[1] + rsum[2] + rsum[3];
            ws_i[CNT_OFF + b] = rcnt[0] + rcnt[1] + rcnt[2] + rcnt[3];
        }
    } else if (bid < 192) {                           // ---- pos pairs: 4 pairs/wave-step ----
        const int w = (bid - 64) * 4 + wv;            // wave id [0,512), 8 pairs each
        const int sub = lane >> 4, sl = lane & 15;
        float contrib = 0.f;
#pragma unroll
        for (int st = 0; st < 2; ++st) {
            int p = w * 8 + st * 4 + sub;
            int q = pos[2 * p], d = pos[2 * p + 1];
            const float4* rq = (const float4*)(bin + (long)q * L_SZ);
            const float4* rd = (const float4*)(bin + (long)d * L_SZ);
            float4 a0 = rq[sl], a1 = rq[sl + 16];
            float4 b0 = rd[sl], b1 = rd[sl + 16];
            float s = a0.x * b0.x + a0.y * b0.y + a0.z * b0.z + a0.w * b0.w
                    + a1.x * b1.x + a1.y * b1.y + a1.z * b1.z + a1.w * b1.w;
            s += __shfl_down(s, 8); s += __shfl_down(s, 4);
            s += __shfl_down(s, 2); s += __shfl_down(s, 1);
            if (sl == 0) { float m = fmaxf(MARGIN - s, 0.f); contrib += m * m; }
        }
        contrib += __shfl_down(contrib, 16);          // lanes 0,16,32,48 -> lane 0
        contrib += __shfl_down(contrib, 32);
        if (lane == 0) ws_f[POS_OFF + w] = contrib;
    } else if (bid < 320) {                           // ---- quant ----
        int idx = (bid - 192) * 256 + tid;
        const float4* c4 = (const float4*)cont;
        float s = 0.f;
#pragma unroll
        for (int k = 0; k < 8; ++k) {
            float4 v = c4[idx + k * 32768];
            s += fabsf(fabsf(v.x) - 1.f) + fabsf(fabsf(v.y) - 1.f) +
                 fabsf(fabsf(v.z) - 1.f) + fabsf(fabsf(v.w) - 1.f);
        }
#pragma unroll
        for (int o = 32; o; o >>= 1) s += __shfl_down(s, o);
        __shared__ float sw[4];
        if (lane == 0) sw[wv] = s;
        __syncthreads();
        if (tid == 0) ws_f[QUANT_OFF + (bid - 192)] = sw[0] + sw[1] + sw[2] + sw[3];
    } else {                                          // ---- bit colsums ----
        int b = bid - 320;                            // 64 blocks x 128 rows
        int col = tid & 127, half = tid >> 7;
        long base = (long)b * 128;
        float s = 0.f;
        for (int r = half; r < 128; r += 2)
            s += bin[(base + r) * L_SZ + col];
        __shared__ float sh[256];
        sh[tid] = s;
        __syncthreads();
        if (tid < 128) ws_f[BITS_OFF + b * 128 + tid] = sh[tid] + sh[tid + 128];
    }
}

// ---- Kernel B: tiny finale — 64-count scan, cutoff rewalk, combine -------
__global__ __launch_bounds__(256) void k_fin(const void* __restrict__ wsv,
                                             float* __restrict__ out) {
    const float* ws_f = (const float*)wsv;
    const int* ws_i = (const int*)wsv;
    const int t = threadIdx.x, lane = t & 63, wv = t >> 6;
    __shared__ int meta[2];                           // cstar, rem
    __shared__ int wtot[4], woff_s[4];
    __shared__ float sh[256];
    __shared__ float fred[4];

    if (wv == 0) {                                    // scan 64 block counts
        int c = ws_i[CNT_OFF + lane];
        int x = c;
#pragma unroll
        for (int o = 1; o < 64; o <<= 1) {
            int y = __shfl_up(x, o);
            if (lane >= o) x += y;
        }
        if ((x - c) < P_PAIRS && x >= P_PAIRS) {      // unique crossing lane
            meta[0] = lane; meta[1] = P_PAIRS - (x - c);
        }
    }
    __syncthreads();
    const int cstar = meta[0], rem = meta[1];

    // rank within cutoff block via ballot scan over 256 entries
    unsigned long long cw =
        ((const unsigned long long*)(ws_i + CB_OFF))[cstar * 4 + wv];
    const bool cand = (cw >> lane) & 1ull;
    unsigned long long bm = __ballot(cand);
    int rw = __popcll(bm & ((1ull << lane) - 1ull));
    if (lane == 63) wtot[wv] = __popcll(bm);
    __syncthreads();
    if (t == 0) { int s = 0; for (int w = 0; w < 4; ++w) { woff_s[w] = s; s += wtot[w]; } }
    __syncthreads();
    const int rank = woff_s[wv] + rw;

    const float inv2p = 1.0f / (float)(2 * P_PAIRS);
    float val = 0.f;
    if (cand && rank < rem) {
        float g = ws_f[GRAM_OFF + cstar * 256 + t];
        float u = fmaxf(g + MARGIN, 0.f);
        val += u * u * inv2p;
    }
    if (t < 64 && t < cstar) val += ws_f[VSUM_OFF + t] * inv2p;
    val += (ws_f[POS_OFF + t] + ws_f[POS_OFF + 256 + t]) * inv2p;
    if (t < 128) val += ws_f[QUANT_OFF + t] * (0.5f / (float)(B_SZ * L_SZ));

    {   // bit-balance: 64 partials per col
        int col = t & 127, g = t >> 7;
        float s2 = 0.f;
        for (int b = g * 32; b < g * 32 + 32; ++b) s2 += ws_f[BITS_OFF + b * 128 + col];
        sh[t] = s2;
    }
    __syncthreads();
    if (t < 128) {
        float cs = sh[t] + sh[t + 128];
        float m = cs * (1.0f / (float)B_SZ);
        val += 0.1f * m * m;
    }
    __syncthreads();
#pragma unroll
    for (int o = 32; o; o >>= 1) val += __shfl_down(val, o);
    if (lane == 0) fred[wv] = val;
    __syncthreads();
    if (t == 0) out[0] = fred[0] + fred[1] + fred[2] + fred[3];
}

extern "C" void kernel_launch(void* const* d_in, const int* in_sizes, int n_in,
                              void* d_out, int out_size, void* d_ws, size_t ws_size,
                              hipStream_t stream) {
    const float* bin = (const float*)d_in[0];
    const float* cont = (const float*)d_in[1];
    const int* pos = (const int*)d_in[2];
    float* out = (float*)d_out;

    k_all<<<384, 256, 0, stream>>>(bin, cont, pos, d_ws);
    k_fin<<<1, 256, 0, stream>>>(d_ws, out);
}